// Round 1
// 326.153 us; speedup vs baseline: 1.0827x; 1.0827x over previous
//
#include <hip/hip_runtime.h>
#include <hip/hip_bf16.h>

// Single-head causal attention. fp32 in, fp32 out. B=4, T=4096, C=2048, HS=128.
//
// R6: flash_partial was latency-bound (MfmaUtil 7.4%, VALUBusy 25%, HBM 7.7%,
// occ 19%). Three changes to the flash body, everything else untouched:
//  1. Register-prefetch double-buffering: issue tile k+1's K/V global loads
//     into 32 VGPRs right after the stage barrier; LDS-write them at the next
//     loop top. Hides global latency under QK/softmax/PV.
//  2. l-sum via MFMA: Vs gets 16 all-ones rows (128..143); PV loop runs dt=0..8
//     and of[8] accumulates row-sums of P with the same alpha recurrence as O.
//     Deletes the 4-step __shfl_xor sum tree (+2 MFMA/tile instead).
//  3. Defer-max (THR=8): skip the O-rescale + m update when no row max grew
//     by >8 (P bounded by 2^8 — fine in bf16).

#define B_  4
#define T_  4096
#define C_  2048
#define HS_ 128

typedef unsigned short u16;
typedef __attribute__((ext_vector_type(8))) short short8;
typedef __attribute__((ext_vector_type(4))) float floatx4;

static __device__ __forceinline__ u16 f2bf(float x) {
  union { float f; unsigned u; } c; c.f = x;
  unsigned r = 0x7fffu + ((c.u >> 16) & 1u);
  return (u16)((c.u + r) >> 16);
}
static __device__ __forceinline__ u16 cvt_elem(float x) { return f2bf(x); }
static __device__ __forceinline__ u16 cvt_elem(u16 x) { return x; }

// ---------------------------------------------------------------- transpose
template <typename ST>
__global__ __launch_bounds__(256) void transpose_kernel(
    const ST* __restrict__ src, u16* __restrict__ dst, int R, int C) {
  __shared__ u16 tile[32][33];
  size_t moff = (size_t)blockIdx.z * (size_t)R * (size_t)C;
  src += moff; dst += moff;
  int c0 = blockIdx.x * 32, r0 = blockIdx.y * 32;
  int tx = threadIdx.x, ty = threadIdx.y;  // block (32, 8)
#pragma unroll
  for (int i = 0; i < 4; ++i)
    tile[ty + 8 * i][tx] = cvt_elem(src[(size_t)(r0 + ty + 8 * i) * C + (c0 + tx)]);
  __syncthreads();
#pragma unroll
  for (int i = 0; i < 4; ++i)
    dst[(size_t)(c0 + ty + 8 * i) * R + (r0 + tx)] = tile[tx][ty + 8 * i];
}

// ---------------------------------------------------------------- QKV GEMM
// (unchanged from R4/R5 — counters not yet visible; profile next round)
#define GBM 128
#define GBK 64
#define LPAD 72

__global__ __launch_bounds__(256) void qkv_gemm_kernel(
    const float* __restrict__ X, const u16* __restrict__ WT3,
    u16* __restrict__ qkv) {
  __shared__ u16 Xs[GBM][LPAD];
  __shared__ u16 Ws[HS_][LPAD];
  int z = blockIdx.y;
  const u16* Wt = WT3 + (size_t)z * HS_ * C_;
  u16* outp = qkv + (size_t)z * ((size_t)B_ * T_ * HS_);
  int t = threadIdx.x;
  int wv = t >> 6, lane = t & 63;
  int l15 = lane & 15, hi = lane >> 4;
  int wm = (wv & 1) * 64, wn = (wv >> 1) * 64;
  size_t mbase = (size_t)blockIdx.x * GBM;

  floatx4 acc[4][4];
#pragma unroll
  for (int i = 0; i < 4; ++i)
#pragma unroll
    for (int j = 0; j < 4; ++j) acc[i][j] = (floatx4){0.f, 0.f, 0.f, 0.f};

  for (int kt = 0; kt < C_ / GBK; ++kt) {
#pragma unroll
    for (int i = 0; i < 4; ++i) {
      int id = i * 256 + t;
      int m = id >> 3, c = id & 7;
      const float* sp = &X[(mbase + m) * C_ + kt * GBK + c * 8];
      short8 v;
#pragma unroll
      for (int j = 0; j < 8; ++j) v[j] = (short)f2bf(sp[j]);
      *(short8*)&Xs[m][c * 8] = v;
    }
#pragma unroll
    for (int i = 0; i < 4; ++i) {
      int id = i * 256 + t;
      int n = id >> 3, c = id & 7;
      *(short8*)&Ws[n][c * 8] =
          *(const short8*)&Wt[(size_t)n * C_ + kt * GBK + c * 8];
    }
    __syncthreads();
#pragma unroll
    for (int ks = 0; ks < 2; ++ks) {
      short8 af[4], bf[4];
#pragma unroll
      for (int mt = 0; mt < 4; ++mt)
        af[mt] = *(const short8*)&Xs[wm + mt * 16 + l15][ks * 32 + hi * 8];
#pragma unroll
      for (int nt = 0; nt < 4; ++nt)
        bf[nt] = *(const short8*)&Ws[wn + nt * 16 + l15][ks * 32 + hi * 8];
#pragma unroll
      for (int mt = 0; mt < 4; ++mt)
#pragma unroll
        for (int nt = 0; nt < 4; ++nt)
          acc[mt][nt] = __builtin_amdgcn_mfma_f32_16x16x32_bf16(
              af[mt], bf[nt], acc[mt][nt], 0, 0, 0);
    }
    __syncthreads();
  }
#pragma unroll
  for (int mt = 0; mt < 4; ++mt)
#pragma unroll
    for (int nt = 0; nt < 4; ++nt)
#pragma unroll
      for (int r = 0; r < 4; ++r) {
        size_t row = mbase + wm + mt * 16 + hi * 4 + r;
        int col = wn + nt * 16 + l15;
        outp[row * HS_ + col] = f2bf(acc[mt][nt][r]);
      }
}

// ---------------------------------------------------------------- flash core
#define BQ 64
#define BKV 64
#define CHUNK 16  // KV tiles per split-KV block (1024 keys)

// Shared body: processes kv tiles [kb0, kb1] for (b, qb). If WRITE_PARTIAL,
// writes unnormalized O + (m,l); else normalizes and writes fp32 out.
template <bool WRITE_PARTIAL>
static __device__ __forceinline__ void flash_body(
    const u16* __restrict__ q, const u16* __restrict__ k,
    const u16* __restrict__ vT, float* __restrict__ outO,
    float* __restrict__ Mp, float* __restrict__ Lp,
    int b, int qb, int kb0, int kb1, int slot) {
  __shared__ u16 Ks[BKV][136];
  __shared__ u16 Vs[144][72];   // rows 0..127: V^T tile; rows 128..143: ones (l-column)
  __shared__ u16 Ps[BQ][72];
  int t = threadIdx.x;
  int wv = t >> 6, lane = t & 63, l15 = lane & 15, hi = lane >> 4;

  const float sc = 0.08838834764831845f * 1.4426950408889634f;

  short8 qf[4];
  {
    const u16* qrow = q + (size_t)(b * T_ + qb * BQ + wv * 16 + l15) * HS_;
#pragma unroll
    for (int ks = 0; ks < 4; ++ks)
      qf[ks] = *(const short8*)(qrow + ks * 32 + hi * 8);
  }

  // ones rows for MFMA l-accumulation: rows 128..143, cols 0..63 used by PV.
  {
    int r = 128 + (t >> 4), c0 = (t & 15) * 4;
    const u16 one = 0x3F80;  // bf16 1.0
    Vs[r][c0] = one; Vs[r][c0 + 1] = one;
    Vs[r][c0 + 2] = one; Vs[r][c0 + 3] = one;
  }

  floatx4 of[9];  // of[0..7] = O; of[8] = l (row-sum column)
#pragma unroll
  for (int dt = 0; dt < 9; ++dt) of[dt] = (floatx4){0.f, 0.f, 0.f, 0.f};
  float m_run[4];
#pragma unroll
  for (int r = 0; r < 4; ++r) m_run[r] = -__builtin_inff();

  const u16* kbase = k + (size_t)b * T_ * HS_;
  const u16* vbase = vT + (size_t)b * HS_ * T_;

  // ---- register prefetch of tile kb0
  short8 kreg[4], vreg[4];
#pragma unroll
  for (int i = 0; i < 4; ++i) {
    int id = i * 256 + t;
    int n = id >> 4, ck = id & 15;
    kreg[i] = *(const short8*)&kbase[(size_t)(kb0 * BKV + n) * HS_ + ck * 8];
    int d = id >> 3, cv = id & 7;
    vreg[i] = *(const short8*)&vbase[(size_t)d * T_ + kb0 * BKV + cv * 8];
  }

  for (int kb = kb0; kb <= kb1; ++kb) {
    // write staged registers -> LDS (vmcnt wait inserted by compiler)
#pragma unroll
    for (int i = 0; i < 4; ++i) {
      int id = i * 256 + t;
      int n = id >> 4, ck = id & 15;
      *(short8*)&Ks[n][ck * 8] = kreg[i];
      int d = id >> 3, cv = id & 7;
      *(short8*)&Vs[d][cv * 8] = vreg[i];
    }
    __syncthreads();

    // issue next tile's global loads early; results not needed until next
    // loop top, so their latency hides under QK/softmax/PV below.
    if (kb < kb1) {
#pragma unroll
      for (int i = 0; i < 4; ++i) {
        int id = i * 256 + t;
        int n = id >> 4, ck = id & 15;
        kreg[i] = *(const short8*)&kbase[(size_t)((kb + 1) * BKV + n) * HS_ + ck * 8];
        int d = id >> 3, cv = id & 7;
        vreg[i] = *(const short8*)&vbase[(size_t)d * T_ + (kb + 1) * BKV + cv * 8];
      }
    }

    floatx4 sf[4];
#pragma unroll
    for (int nt = 0; nt < 4; ++nt) {
      floatx4 s = (floatx4){0.f, 0.f, 0.f, 0.f};
#pragma unroll
      for (int ks = 0; ks < 4; ++ks) {
        short8 bfrag = *(const short8*)&Ks[nt * 16 + l15][ks * 32 + hi * 8];
        s = __builtin_amdgcn_mfma_f32_16x16x32_bf16(qf[ks], bfrag, s, 0, 0, 0);
      }
      sf[nt] = s;
    }

    float sv[4][4];
    if (kb == qb) {
#pragma unroll
      for (int nt = 0; nt < 4; ++nt) {
        int col = nt * 16 + l15;
#pragma unroll
        for (int r = 0; r < 4; ++r) {
          int row = wv * 16 + hi * 4 + r;
          sv[nt][r] = (col <= row) ? sf[nt][r] * sc : -__builtin_inff();
        }
      }
    } else {
#pragma unroll
      for (int nt = 0; nt < 4; ++nt)
#pragma unroll
        for (int r = 0; r < 4; ++r) sv[nt][r] = sf[nt][r] * sc;
    }

    // per-row max (4-step butterfly over the 16-lane group)
    float mt4[4];
#pragma unroll
    for (int r = 0; r < 4; ++r)
      mt4[r] = fmaxf(fmaxf(sv[0][r], sv[1][r]), fmaxf(sv[2][r], sv[3][r]));
#pragma unroll
    for (int off = 1; off < 16; off <<= 1)
#pragma unroll
      for (int r = 0; r < 4; ++r)
        mt4[r] = fmaxf(mt4[r], __shfl_xor(mt4[r], off));

    // defer-max: only rescale when a row max grew by > 8 (P bounded by 2^8)
    bool need = false;
#pragma unroll
    for (int r = 0; r < 4; ++r) need = need || (mt4[r] > m_run[r] + 8.f);
    if (__any(need)) {
      float alpha[4];
#pragma unroll
      for (int r = 0; r < 4; ++r) {
        float mn = fmaxf(m_run[r], mt4[r]);
        alpha[r] = exp2f(m_run[r] - mn);
        m_run[r] = mn;
      }
#pragma unroll
      for (int dt = 0; dt < 9; ++dt)
#pragma unroll
        for (int r = 0; r < 4; ++r) of[dt][r] *= alpha[r];
    }

    float pv[4][4];
#pragma unroll
    for (int nt = 0; nt < 4; ++nt)
#pragma unroll
      for (int r = 0; r < 4; ++r) pv[nt][r] = exp2f(sv[nt][r] - m_run[r]);

#pragma unroll
    for (int nt = 0; nt < 4; ++nt)
#pragma unroll
      for (int r = 0; r < 4; ++r)
        Ps[wv * 16 + hi * 4 + r][nt * 16 + l15] = f2bf(pv[nt][r]);
    __asm__ volatile("s_waitcnt lgkmcnt(0)" ::: "memory");

#pragma unroll
    for (int ks2 = 0; ks2 < 2; ++ks2) {
      short8 af = *(const short8*)&Ps[wv * 16 + l15][ks2 * 32 + hi * 8];
#pragma unroll
      for (int dt = 0; dt < 9; ++dt) {
        short8 bfrag = *(const short8*)&Vs[dt * 16 + l15][ks2 * 32 + hi * 8];
        of[dt] = __builtin_amdgcn_mfma_f32_16x16x32_bf16(af, bfrag, of[dt], 0, 0, 0);
      }
    }
    __syncthreads();
  }

  if (WRITE_PARTIAL) {
    float* Op = outO + (size_t)slot * (BQ * HS_);
#pragma unroll
    for (int dt = 0; dt < 8; ++dt)
#pragma unroll
      for (int r = 0; r < 4; ++r) {
        int row = wv * 16 + hi * 4 + r;
        Op[row * HS_ + dt * 16 + l15] = of[dt][r];
      }
    if (l15 == 0) {
#pragma unroll
      for (int r = 0; r < 4; ++r) {
        int row = wv * 16 + hi * 4 + r;
        Mp[slot * BQ + row] = m_run[r];
        Lp[slot * BQ + row] = of[8][r];  // l accumulated by MFMA ones-column
      }
    }
  } else {
    float rl[4];
#pragma unroll
    for (int r = 0; r < 4; ++r) rl[r] = 1.0f / of[8][r];
#pragma unroll
    for (int dt = 0; dt < 8; ++dt)
#pragma unroll
      for (int r = 0; r < 4; ++r) {
        size_t row = (size_t)(b * T_ + qb * BQ + wv * 16 + hi * 4 + r);
        outO[row * HS_ + dt * 16 + l15] = of[dt][r] * rl[r];
      }
  }
}

// split-KV partial: grid (64 qb, 4 chunk, 4 batch)
__global__ __launch_bounds__(256, 3) void flash_partial_kernel(
    const u16* __restrict__ q, const u16* __restrict__ k,
    const u16* __restrict__ vT, float* __restrict__ Opart,
    float* __restrict__ Mpart, float* __restrict__ Lpart) {
  int qb = blockIdx.x, c = blockIdx.y, b = blockIdx.z;
  int kb0 = c * CHUNK;
  if (kb0 > qb) return;  // empty chunk
  int kb1 = min(qb, kb0 + CHUNK - 1);
  int slot = (b * (T_ / BQ) + qb) * 4 + c;
  flash_body<true>(q, k, vT, Opart, Mpart, Lpart, b, qb, kb0, kb1, slot);
}

// monolithic fallback (R4-proven): grid (64 qb, 4 batch)
__global__ __launch_bounds__(256, 3) void flash_attn_kernel(
    const u16* __restrict__ q, const u16* __restrict__ k,
    const u16* __restrict__ vT, float* __restrict__ out) {
  int qb = blockIdx.x, b = blockIdx.y;
  flash_body<false>(q, k, vT, out, nullptr, nullptr, b, qb, 0, qb, 0);
}

// merge: grid (64 qb, 4 batch), 256 threads
__global__ __launch_bounds__(256) void flash_merge_kernel(
    const float* __restrict__ Opart, const float* __restrict__ Mpart,
    const float* __restrict__ Lpart, float* __restrict__ out) {
  __shared__ float w[4][BQ];
  __shared__ float invL[BQ];
  int qb = blockIdx.x, b = blockIdx.y;
  int t = threadIdx.x;
  int nch = qb / CHUNK + 1;  // 1..4
  int slot0 = (b * (T_ / BQ) + qb) * 4;

  if (t < BQ) {
    float mv[4], mmax = -__builtin_inff();
    for (int c = 0; c < nch; ++c) {
      mv[c] = Mpart[(slot0 + c) * BQ + t];
      mmax = fmaxf(mmax, mv[c]);
    }
    float L = 0.f;
    for (int c = 0; c < nch; ++c) {
      float wc = exp2f(mv[c] - mmax);
      w[c][t] = wc;
      L += wc * Lpart[(slot0 + c) * BQ + t];
    }
    invL[t] = 1.0f / L;
  }
  __syncthreads();

  size_t obase = ((size_t)(b * T_) + (size_t)qb * BQ) * HS_;
#pragma unroll
  for (int j = 0; j < 32; ++j) {
    int e = j * 256 + t;           // 0..8191
    int row = e >> 7;
    float acc = 0.f;
    for (int c = 0; c < nch; ++c)
      acc += w[c][row] * Opart[(size_t)(slot0 + c) * (BQ * HS_) + e];
    out[obase + e] = acc * invL[row];
  }
}

// ---------------------------------------------------------------- launch
extern "C" void kernel_launch(void* const* d_in, const int* in_sizes, int n_in,
                              void* d_out, int out_size, void* d_ws, size_t ws_size,
                              hipStream_t stream) {
  const float* x  = (const float*)d_in[0];
  const float* Wq = (const float*)d_in[1];
  const float* Wk = (const float*)d_in[2];
  const float* Wv = (const float*)d_in[3];
  float* out = (float*)d_out;

  u16* ws = (u16*)d_ws;
  const size_t wtsz  = (size_t)HS_ * C_;
  const size_t qkvsz = (size_t)B_ * T_ * HS_;
  u16* WT = ws;
  u16* qv = WT + 3 * wtsz;
  u16* kv = qv + qkvsz;
  u16* vv = kv + qkvsz;
  u16* vT = vv + qkvsz;
  const size_t base_bytes = (3 * wtsz + 4 * qkvsz) * sizeof(u16);  // 18,350,080

  const int NSLOT = B_ * (T_ / BQ) * 4;  // 1024
  float* Opart = (float*)((char*)d_ws + base_bytes);
  float* Mpart = Opart + (size_t)NSLOT * BQ * HS_;
  float* Lpart = Mpart + (size_t)NSLOT * BQ;
  const size_t split_bytes =
      base_bytes + ((size_t)NSLOT * BQ * HS_ + 2 * (size_t)NSLOT * BQ) * sizeof(float);

  dim3 tb(32, 8);
  transpose_kernel<float><<<dim3(HS_ / 32, C_ / 32, 1), tb, 0, stream>>>(Wq, WT + 0 * wtsz, C_, HS_);
  transpose_kernel<float><<<dim3(HS_ / 32, C_ / 32, 1), tb, 0, stream>>>(Wk, WT + 1 * wtsz, C_, HS_);
  transpose_kernel<float><<<dim3(HS_ / 32, C_ / 32, 1), tb, 0, stream>>>(Wv, WT + 2 * wtsz, C_, HS_);

  qkv_gemm_kernel<<<dim3((B_ * T_) / GBM, 3), 256, 0, stream>>>(x, WT, qv);

  transpose_kernel<u16><<<dim3(HS_ / 32, T_ / 32, B_), tb, 0, stream>>>(vv, vT, T_, HS_);

  if (ws_size >= split_bytes) {
    flash_partial_kernel<<<dim3(T_ / BQ, 4, B_), 256, 0, stream>>>(
        qv, kv, vT, Opart, Mpart, Lpart);
    flash_merge_kernel<<<dim3(T_ / BQ, B_), 256, 0, stream>>>(
        Opart, Mpart, Lpart, out);
  } else {
    flash_attn_kernel<<<dim3(T_ / BQ, B_), 256, 0, stream>>>(qv, kv, vT, out);
  }
}

// Round 2
// 316.202 us; speedup vs baseline: 1.1168x; 1.0315x over previous
//
#include <hip/hip_runtime.h>
#include <hip/hip_bf16.h>

// Single-head causal attention. fp32 in, fp32 out. B=4, T=4096, C=2048, HS=128.
//
// R7: qkv_gemm was the new #1 (85 us, MfmaUtil 11.5%, occ 15.4% -- grid-capped
// at 384 blocks / 256 CUs, serial K-loop). Changes (GEMM only, flash untouched):
//  1. GBM 128->64: grid 384->768 blocks (~3/CU), LDS 36.9->27.6 KB.
//  2. Register-prefetch double-buffering in the K-loop (same pattern that won
//     in flash R6): issue kt+1's global loads after the stage barrier, write
//     to LDS at next loop top.
//  3. Explicit float4 loads for X staging (was 8 scalar fp32 loads).

#define B_  4
#define T_  4096
#define C_  2048
#define HS_ 128

typedef unsigned short u16;
typedef __attribute__((ext_vector_type(8))) short short8;
typedef __attribute__((ext_vector_type(4))) float floatx4;

static __device__ __forceinline__ u16 f2bf(float x) {
  union { float f; unsigned u; } c; c.f = x;
  unsigned r = 0x7fffu + ((c.u >> 16) & 1u);
  return (u16)((c.u + r) >> 16);
}
static __device__ __forceinline__ u16 cvt_elem(float x) { return f2bf(x); }
static __device__ __forceinline__ u16 cvt_elem(u16 x) { return x; }

// ---------------------------------------------------------------- transpose
template <typename ST>
__global__ __launch_bounds__(256) void transpose_kernel(
    const ST* __restrict__ src, u16* __restrict__ dst, int R, int C) {
  __shared__ u16 tile[32][33];
  size_t moff = (size_t)blockIdx.z * (size_t)R * (size_t)C;
  src += moff; dst += moff;
  int c0 = blockIdx.x * 32, r0 = blockIdx.y * 32;
  int tx = threadIdx.x, ty = threadIdx.y;  // block (32, 8)
#pragma unroll
  for (int i = 0; i < 4; ++i)
    tile[ty + 8 * i][tx] = cvt_elem(src[(size_t)(r0 + ty + 8 * i) * C + (c0 + tx)]);
  __syncthreads();
#pragma unroll
  for (int i = 0; i < 4; ++i)
    dst[(size_t)(c0 + ty + 8 * i) * R + (r0 + tx)] = tile[tx][ty + 8 * i];
}

// ---------------------------------------------------------------- QKV GEMM
#define GBM 64
#define GBK 64
#define LPAD 72

__global__ __launch_bounds__(256) void qkv_gemm_kernel(
    const float* __restrict__ X, const u16* __restrict__ WT3,
    u16* __restrict__ qkv) {
  __shared__ u16 Xs[GBM][LPAD];
  __shared__ u16 Ws[HS_][LPAD];
  int z = blockIdx.y;
  const u16* Wt = WT3 + (size_t)z * HS_ * C_;
  u16* outp = qkv + (size_t)z * ((size_t)B_ * T_ * HS_);
  int t = threadIdx.x;
  int wv = t >> 6, lane = t & 63;
  int l15 = lane & 15, hi = lane >> 4;
  int wm = (wv & 1) * 32, wn = (wv >> 1) * 64;
  size_t mbase = (size_t)blockIdx.x * GBM;

  // staging decomposition: X rows xm/xm+32, W rows i*32+xm, col chunk xc
  int xm = t >> 3, xc = t & 7;

  const float* xrow0 = &X[(mbase + xm) * C_];
  const float* xrow1 = &X[(mbase + 32 + xm) * C_];
  const u16* wrow0 = &Wt[(size_t)(xm) * C_];
  const u16* wrow1 = &Wt[(size_t)(32 + xm) * C_];
  const u16* wrow2 = &Wt[(size_t)(64 + xm) * C_];
  const u16* wrow3 = &Wt[(size_t)(96 + xm) * C_];

  floatx4 acc[2][4];
#pragma unroll
  for (int i = 0; i < 2; ++i)
#pragma unroll
    for (int j = 0; j < 4; ++j) acc[i][j] = (floatx4){0.f, 0.f, 0.f, 0.f};

  // ---- register prefetch of kt=0
  floatx4 xreg[2][2];
  short8 wreg[4];
  {
    int koff = xc * 8;
    xreg[0][0] = *(const floatx4*)&xrow0[koff];
    xreg[0][1] = *(const floatx4*)&xrow0[koff + 4];
    xreg[1][0] = *(const floatx4*)&xrow1[koff];
    xreg[1][1] = *(const floatx4*)&xrow1[koff + 4];
    wreg[0] = *(const short8*)&wrow0[koff];
    wreg[1] = *(const short8*)&wrow1[koff];
    wreg[2] = *(const short8*)&wrow2[koff];
    wreg[3] = *(const short8*)&wrow3[koff];
  }

  for (int kt = 0; kt < C_ / GBK; ++kt) {
    // write staged registers -> LDS
#pragma unroll
    for (int i = 0; i < 2; ++i) {
      short8 v;
#pragma unroll
      for (int j = 0; j < 4; ++j) {
        v[j] = (short)f2bf(xreg[i][0][j]);
        v[4 + j] = (short)f2bf(xreg[i][1][j]);
      }
      *(short8*)&Xs[i * 32 + xm][xc * 8] = v;
    }
    *(short8*)&Ws[xm][xc * 8] = wreg[0];
    *(short8*)&Ws[32 + xm][xc * 8] = wreg[1];
    *(short8*)&Ws[64 + xm][xc * 8] = wreg[2];
    *(short8*)&Ws[96 + xm][xc * 8] = wreg[3];
    __syncthreads();

    // issue next tile's global loads; latency hides under MFMA phase below
    if (kt + 1 < C_ / GBK) {
      int koff = (kt + 1) * GBK + xc * 8;
      xreg[0][0] = *(const floatx4*)&xrow0[koff];
      xreg[0][1] = *(const floatx4*)&xrow0[koff + 4];
      xreg[1][0] = *(const floatx4*)&xrow1[koff];
      xreg[1][1] = *(const floatx4*)&xrow1[koff + 4];
      wreg[0] = *(const short8*)&wrow0[koff];
      wreg[1] = *(const short8*)&wrow1[koff];
      wreg[2] = *(const short8*)&wrow2[koff];
      wreg[3] = *(const short8*)&wrow3[koff];
    }

#pragma unroll
    for (int ks = 0; ks < 2; ++ks) {
      short8 af[2], bf[4];
#pragma unroll
      for (int mt = 0; mt < 2; ++mt)
        af[mt] = *(const short8*)&Xs[wm + mt * 16 + l15][ks * 32 + hi * 8];
#pragma unroll
      for (int nt = 0; nt < 4; ++nt)
        bf[nt] = *(const short8*)&Ws[wn + nt * 16 + l15][ks * 32 + hi * 8];
#pragma unroll
      for (int mt = 0; mt < 2; ++mt)
#pragma unroll
        for (int nt = 0; nt < 4; ++nt)
          acc[mt][nt] = __builtin_amdgcn_mfma_f32_16x16x32_bf16(
              af[mt], bf[nt], acc[mt][nt], 0, 0, 0);
    }
    __syncthreads();
  }
#pragma unroll
  for (int mt = 0; mt < 2; ++mt)
#pragma unroll
    for (int nt = 0; nt < 4; ++nt)
#pragma unroll
      for (int r = 0; r < 4; ++r) {
        size_t row = mbase + wm + mt * 16 + hi * 4 + r;
        int col = wn + nt * 16 + l15;
        outp[row * HS_ + col] = f2bf(acc[mt][nt][r]);
      }
}

// ---------------------------------------------------------------- flash core
#define BQ 64
#define BKV 64
#define CHUNK 16  // KV tiles per split-KV block (1024 keys)

// Shared body: processes kv tiles [kb0, kb1] for (b, qb). If WRITE_PARTIAL,
// writes unnormalized O + (m,l); else normalizes and writes fp32 out.
template <bool WRITE_PARTIAL>
static __device__ __forceinline__ void flash_body(
    const u16* __restrict__ q, const u16* __restrict__ k,
    const u16* __restrict__ vT, float* __restrict__ outO,
    float* __restrict__ Mp, float* __restrict__ Lp,
    int b, int qb, int kb0, int kb1, int slot) {
  __shared__ u16 Ks[BKV][136];
  __shared__ u16 Vs[144][72];   // rows 0..127: V^T tile; rows 128..143: ones (l-column)
  __shared__ u16 Ps[BQ][72];
  int t = threadIdx.x;
  int wv = t >> 6, lane = t & 63, l15 = lane & 15, hi = lane >> 4;

  const float sc = 0.08838834764831845f * 1.4426950408889634f;

  short8 qf[4];
  {
    const u16* qrow = q + (size_t)(b * T_ + qb * BQ + wv * 16 + l15) * HS_;
#pragma unroll
    for (int ks = 0; ks < 4; ++ks)
      qf[ks] = *(const short8*)(qrow + ks * 32 + hi * 8);
  }

  // ones rows for MFMA l-accumulation: rows 128..143, cols 0..63 used by PV.
  {
    int r = 128 + (t >> 4), c0 = (t & 15) * 4;
    const u16 one = 0x3F80;  // bf16 1.0
    Vs[r][c0] = one; Vs[r][c0 + 1] = one;
    Vs[r][c0 + 2] = one; Vs[r][c0 + 3] = one;
  }

  floatx4 of[9];  // of[0..7] = O; of[8] = l (row-sum column)
#pragma unroll
  for (int dt = 0; dt < 9; ++dt) of[dt] = (floatx4){0.f, 0.f, 0.f, 0.f};
  float m_run[4];
#pragma unroll
  for (int r = 0; r < 4; ++r) m_run[r] = -__builtin_inff();

  const u16* kbase = k + (size_t)b * T_ * HS_;
  const u16* vbase = vT + (size_t)b * HS_ * T_;

  // ---- register prefetch of tile kb0
  short8 kreg[4], vreg[4];
#pragma unroll
  for (int i = 0; i < 4; ++i) {
    int id = i * 256 + t;
    int n = id >> 4, ck = id & 15;
    kreg[i] = *(const short8*)&kbase[(size_t)(kb0 * BKV + n) * HS_ + ck * 8];
    int d = id >> 3, cv = id & 7;
    vreg[i] = *(const short8*)&vbase[(size_t)d * T_ + kb0 * BKV + cv * 8];
  }

  for (int kb = kb0; kb <= kb1; ++kb) {
    // write staged registers -> LDS (vmcnt wait inserted by compiler)
#pragma unroll
    for (int i = 0; i < 4; ++i) {
      int id = i * 256 + t;
      int n = id >> 4, ck = id & 15;
      *(short8*)&Ks[n][ck * 8] = kreg[i];
      int d = id >> 3, cv = id & 7;
      *(short8*)&Vs[d][cv * 8] = vreg[i];
    }
    __syncthreads();

    // issue next tile's global loads early; results not needed until next
    // loop top, so their latency hides under QK/softmax/PV below.
    if (kb < kb1) {
#pragma unroll
      for (int i = 0; i < 4; ++i) {
        int id = i * 256 + t;
        int n = id >> 4, ck = id & 15;
        kreg[i] = *(const short8*)&kbase[(size_t)((kb + 1) * BKV + n) * HS_ + ck * 8];
        int d = id >> 3, cv = id & 7;
        vreg[i] = *(const short8*)&vbase[(size_t)d * T_ + (kb + 1) * BKV + cv * 8];
      }
    }

    floatx4 sf[4];
#pragma unroll
    for (int nt = 0; nt < 4; ++nt) {
      floatx4 s = (floatx4){0.f, 0.f, 0.f, 0.f};
#pragma unroll
      for (int ks = 0; ks < 4; ++ks) {
        short8 bfrag = *(const short8*)&Ks[nt * 16 + l15][ks * 32 + hi * 8];
        s = __builtin_amdgcn_mfma_f32_16x16x32_bf16(qf[ks], bfrag, s, 0, 0, 0);
      }
      sf[nt] = s;
    }

    float sv[4][4];
    if (kb == qb) {
#pragma unroll
      for (int nt = 0; nt < 4; ++nt) {
        int col = nt * 16 + l15;
#pragma unroll
        for (int r = 0; r < 4; ++r) {
          int row = wv * 16 + hi * 4 + r;
          sv[nt][r] = (col <= row) ? sf[nt][r] * sc : -__builtin_inff();
        }
      }
    } else {
#pragma unroll
      for (int nt = 0; nt < 4; ++nt)
#pragma unroll
        for (int r = 0; r < 4; ++r) sv[nt][r] = sf[nt][r] * sc;
    }

    // per-row max (4-step butterfly over the 16-lane group)
    float mt4[4];
#pragma unroll
    for (int r = 0; r < 4; ++r)
      mt4[r] = fmaxf(fmaxf(sv[0][r], sv[1][r]), fmaxf(sv[2][r], sv[3][r]));
#pragma unroll
    for (int off = 1; off < 16; off <<= 1)
#pragma unroll
      for (int r = 0; r < 4; ++r)
        mt4[r] = fmaxf(mt4[r], __shfl_xor(mt4[r], off));

    // defer-max: only rescale when a row max grew by > 8 (P bounded by 2^8)
    bool need = false;
#pragma unroll
    for (int r = 0; r < 4; ++r) need = need || (mt4[r] > m_run[r] + 8.f);
    if (__any(need)) {
      float alpha[4];
#pragma unroll
      for (int r = 0; r < 4; ++r) {
        float mn = fmaxf(m_run[r], mt4[r]);
        alpha[r] = exp2f(m_run[r] - mn);
        m_run[r] = mn;
      }
#pragma unroll
      for (int dt = 0; dt < 9; ++dt)
#pragma unroll
        for (int r = 0; r < 4; ++r) of[dt][r] *= alpha[r];
    }

    float pv[4][4];
#pragma unroll
    for (int nt = 0; nt < 4; ++nt)
#pragma unroll
      for (int r = 0; r < 4; ++r) pv[nt][r] = exp2f(sv[nt][r] - m_run[r]);

#pragma unroll
    for (int nt = 0; nt < 4; ++nt)
#pragma unroll
      for (int r = 0; r < 4; ++r)
        Ps[wv * 16 + hi * 4 + r][nt * 16 + l15] = f2bf(pv[nt][r]);
    __asm__ volatile("s_waitcnt lgkmcnt(0)" ::: "memory");

#pragma unroll
    for (int ks2 = 0; ks2 < 2; ++ks2) {
      short8 af = *(const short8*)&Ps[wv * 16 + l15][ks2 * 32 + hi * 8];
#pragma unroll
      for (int dt = 0; dt < 9; ++dt) {
        short8 bfrag = *(const short8*)&Vs[dt * 16 + l15][ks2 * 32 + hi * 8];
        of[dt] = __builtin_amdgcn_mfma_f32_16x16x32_bf16(af, bfrag, of[dt], 0, 0, 0);
      }
    }
    __syncthreads();
  }

  if (WRITE_PARTIAL) {
    float* Op = outO + (size_t)slot * (BQ * HS_);
#pragma unroll
    for (int dt = 0; dt < 8; ++dt)
#pragma unroll
      for (int r = 0; r < 4; ++r) {
        int row = wv * 16 + hi * 4 + r;
        Op[row * HS_ + dt * 16 + l15] = of[dt][r];
      }
    if (l15 == 0) {
#pragma unroll
      for (int r = 0; r < 4; ++r) {
        int row = wv * 16 + hi * 4 + r;
        Mp[slot * BQ + row] = m_run[r];
        Lp[slot * BQ + row] = of[8][r];  // l accumulated by MFMA ones-column
      }
    }
  } else {
    float rl[4];
#pragma unroll
    for (int r = 0; r < 4; ++r) rl[r] = 1.0f / of[8][r];
#pragma unroll
    for (int dt = 0; dt < 8; ++dt)
#pragma unroll
      for (int r = 0; r < 4; ++r) {
        size_t row = (size_t)(b * T_ + qb * BQ + wv * 16 + hi * 4 + r);
        outO[row * HS_ + dt * 16 + l15] = of[dt][r] * rl[r];
      }
  }
}

// split-KV partial: grid (64 qb, 4 chunk, 4 batch)
__global__ __launch_bounds__(256, 3) void flash_partial_kernel(
    const u16* __restrict__ q, const u16* __restrict__ k,
    const u16* __restrict__ vT, float* __restrict__ Opart,
    float* __restrict__ Mpart, float* __restrict__ Lpart) {
  int qb = blockIdx.x, c = blockIdx.y, b = blockIdx.z;
  int kb0 = c * CHUNK;
  if (kb0 > qb) return;  // empty chunk
  int kb1 = min(qb, kb0 + CHUNK - 1);
  int slot = (b * (T_ / BQ) + qb) * 4 + c;
  flash_body<true>(q, k, vT, Opart, Mpart, Lpart, b, qb, kb0, kb1, slot);
}

// monolithic fallback (R4-proven): grid (64 qb, 4 batch)
__global__ __launch_bounds__(256, 3) void flash_attn_kernel(
    const u16* __restrict__ q, const u16* __restrict__ k,
    const u16* __restrict__ vT, float* __restrict__ out) {
  int qb = blockIdx.x, b = blockIdx.y;
  flash_body<false>(q, k, vT, out, nullptr, nullptr, b, qb, 0, qb, 0);
}

// merge: grid (64 qb, 4 batch), 256 threads
__global__ __launch_bounds__(256) void flash_merge_kernel(
    const float* __restrict__ Opart, const float* __restrict__ Mpart,
    const float* __restrict__ Lpart, float* __restrict__ out) {
  __shared__ float w[4][BQ];
  __shared__ float invL[BQ];
  int qb = blockIdx.x, b = blockIdx.y;
  int t = threadIdx.x;
  int nch = qb / CHUNK + 1;  // 1..4
  int slot0 = (b * (T_ / BQ) + qb) * 4;

  if (t < BQ) {
    float mv[4], mmax = -__builtin_inff();
    for (int c = 0; c < nch; ++c) {
      mv[c] = Mpart[(slot0 + c) * BQ + t];
      mmax = fmaxf(mmax, mv[c]);
    }
    float L = 0.f;
    for (int c = 0; c < nch; ++c) {
      float wc = exp2f(mv[c] - mmax);
      w[c][t] = wc;
      L += wc * Lpart[(slot0 + c) * BQ + t];
    }
    invL[t] = 1.0f / L;
  }
  __syncthreads();

  size_t obase = ((size_t)(b * T_) + (size_t)qb * BQ) * HS_;
#pragma unroll
  for (int j = 0; j < 32; ++j) {
    int e = j * 256 + t;           // 0..8191
    int row = e >> 7;
    float acc = 0.f;
    for (int c = 0; c < nch; ++c)
      acc += w[c][row] * Opart[(size_t)(slot0 + c) * (BQ * HS_) + e];
    out[obase + e] = acc * invL[row];
  }
}

// ---------------------------------------------------------------- launch
extern "C" void kernel_launch(void* const* d_in, const int* in_sizes, int n_in,
                              void* d_out, int out_size, void* d_ws, size_t ws_size,
                              hipStream_t stream) {
  const float* x  = (const float*)d_in[0];
  const float* Wq = (const float*)d_in[1];
  const float* Wk = (const float*)d_in[2];
  const float* Wv = (const float*)d_in[3];
  float* out = (float*)d_out;

  u16* ws = (u16*)d_ws;
  const size_t wtsz  = (size_t)HS_ * C_;
  const size_t qkvsz = (size_t)B_ * T_ * HS_;
  u16* WT = ws;
  u16* qv = WT + 3 * wtsz;
  u16* kv = qv + qkvsz;
  u16* vv = kv + qkvsz;
  u16* vT = vv + qkvsz;
  const size_t base_bytes = (3 * wtsz + 4 * qkvsz) * sizeof(u16);  // 18,350,080

  const int NSLOT = B_ * (T_ / BQ) * 4;  // 1024
  float* Opart = (float*)((char*)d_ws + base_bytes);
  float* Mpart = Opart + (size_t)NSLOT * BQ * HS_;
  float* Lpart = Mpart + (size_t)NSLOT * BQ;
  const size_t split_bytes =
      base_bytes + ((size_t)NSLOT * BQ * HS_ + 2 * (size_t)NSLOT * BQ) * sizeof(float);

  dim3 tb(32, 8);
  transpose_kernel<float><<<dim3(HS_ / 32, C_ / 32, 1), tb, 0, stream>>>(Wq, WT + 0 * wtsz, C_, HS_);
  transpose_kernel<float><<<dim3(HS_ / 32, C_ / 32, 1), tb, 0, stream>>>(Wk, WT + 1 * wtsz, C_, HS_);
  transpose_kernel<float><<<dim3(HS_ / 32, C_ / 32, 1), tb, 0, stream>>>(Wv, WT + 2 * wtsz, C_, HS_);

  qkv_gemm_kernel<<<dim3((B_ * T_) / GBM, 3), 256, 0, stream>>>(x, WT, qv);

  transpose_kernel<u16><<<dim3(HS_ / 32, T_ / 32, B_), tb, 0, stream>>>(vv, vT, T_, HS_);

  if (ws_size >= split_bytes) {
    flash_partial_kernel<<<dim3(T_ / BQ, 4, B_), 256, 0, stream>>>(
        qv, kv, vT, Opart, Mpart, Lpart);
    flash_merge_kernel<<<dim3(T_ / BQ, B_), 256, 0, stream>>>(
        Opart, Mpart, Lpart, out);
  } else {
    flash_attn_kernel<<<dim3(T_ / BQ, B_), 256, 0, stream>>>(qv, kv, vT, out);
  }
}

// Round 3
// 306.931 us; speedup vs baseline: 1.1506x; 1.0302x over previous
//
#include <hip/hip_runtime.h>
#include <hip/hip_bf16.h>

// Single-head causal attention. fp32 in, fp32 out. B=4, T=4096, C=2048, HS=128.
//
// R8: profile view is saturated by harness fillBuffer dispatches (all our
// kernels < 77 us). Structural cleanup round:
//  1. V^T fused into qkv_gemm epilogue (z==2): each block's 64x128 output tile
//     is transposed in LDS (reusing the staging buffer) and written as
//     contiguous 128B segments of vT. Removes the standalone V-transpose
//     kernel (full extra pass over V) + its launch.
//  2. The 3 weight-transpose launches fused into one (blockIdx.z selects W).
//  3. Flash body unchanged from R6 (reg-prefetch + MFMA l-sum + defer-max).

#define B_  4
#define T_  4096
#define C_  2048
#define HS_ 128

typedef unsigned short u16;
typedef __attribute__((ext_vector_type(8))) short short8;
typedef __attribute__((ext_vector_type(4))) float floatx4;

static __device__ __forceinline__ u16 f2bf(float x) {
  union { float f; unsigned u; } c; c.f = x;
  unsigned r = 0x7fffu + ((c.u >> 16) & 1u);
  return (u16)((c.u + r) >> 16);
}

// ---------------------------------------------------------------- W^T (x3)
__global__ __launch_bounds__(256) void wtrans3_kernel(
    const float* __restrict__ Wq, const float* __restrict__ Wk,
    const float* __restrict__ Wv, u16* __restrict__ dst) {
  __shared__ u16 tile[32][33];
  int z = blockIdx.z;
  const float* src = (z == 0) ? Wq : (z == 1) ? Wk : Wv;
  u16* d = dst + (size_t)z * HS_ * C_;
  int c0 = blockIdx.x * 32, r0 = blockIdx.y * 32;  // c over HS_, r over C_
  int tx = threadIdx.x, ty = threadIdx.y;          // block (32, 8)
#pragma unroll
  for (int i = 0; i < 4; ++i)
    tile[ty + 8 * i][tx] = f2bf(src[(size_t)(r0 + ty + 8 * i) * HS_ + (c0 + tx)]);
  __syncthreads();
#pragma unroll
  for (int i = 0; i < 4; ++i)
    d[(size_t)(c0 + ty + 8 * i) * C_ + (r0 + tx)] = tile[tx][ty + 8 * i];
}

// ---------------------------------------------------------------- QKV GEMM
#define GBM 64
#define GBK 64
#define LPAD 72

__global__ __launch_bounds__(256) void qkv_gemm_kernel(
    const float* __restrict__ X, const u16* __restrict__ WT3,
    u16* __restrict__ qkv, u16* __restrict__ vT) {
  // single shared pool; Xs/Ws carved out, reused as transpose buffer in the
  // z==2 epilogue (27.6 KB total, >= 128*72 u16 needed for the transpose).
  __shared__ u16 smem[GBM * LPAD + HS_ * LPAD];
  u16 (*Xs)[LPAD] = (u16(*)[LPAD])smem;
  u16 (*Ws)[LPAD] = (u16(*)[LPAD])(smem + GBM * LPAD);

  int z = blockIdx.y;
  const u16* Wt = WT3 + (size_t)z * HS_ * C_;
  int t = threadIdx.x;
  int wv = t >> 6, lane = t & 63;
  int l15 = lane & 15, hi = lane >> 4;
  int wm = (wv & 1) * 32, wn = (wv >> 1) * 64;
  size_t mbase = (size_t)blockIdx.x * GBM;

  int xm = t >> 3, xc = t & 7;

  const float* xrow0 = &X[(mbase + xm) * C_];
  const float* xrow1 = &X[(mbase + 32 + xm) * C_];
  const u16* wrow0 = &Wt[(size_t)(xm) * C_];
  const u16* wrow1 = &Wt[(size_t)(32 + xm) * C_];
  const u16* wrow2 = &Wt[(size_t)(64 + xm) * C_];
  const u16* wrow3 = &Wt[(size_t)(96 + xm) * C_];

  floatx4 acc[2][4];
#pragma unroll
  for (int i = 0; i < 2; ++i)
#pragma unroll
    for (int j = 0; j < 4; ++j) acc[i][j] = (floatx4){0.f, 0.f, 0.f, 0.f};

  // ---- register prefetch of kt=0
  floatx4 xreg[2][2];
  short8 wreg[4];
  {
    int koff = xc * 8;
    xreg[0][0] = *(const floatx4*)&xrow0[koff];
    xreg[0][1] = *(const floatx4*)&xrow0[koff + 4];
    xreg[1][0] = *(const floatx4*)&xrow1[koff];
    xreg[1][1] = *(const floatx4*)&xrow1[koff + 4];
    wreg[0] = *(const short8*)&wrow0[koff];
    wreg[1] = *(const short8*)&wrow1[koff];
    wreg[2] = *(const short8*)&wrow2[koff];
    wreg[3] = *(const short8*)&wrow3[koff];
  }

  for (int kt = 0; kt < C_ / GBK; ++kt) {
    // write staged registers -> LDS
#pragma unroll
    for (int i = 0; i < 2; ++i) {
      short8 v;
#pragma unroll
      for (int j = 0; j < 4; ++j) {
        v[j] = (short)f2bf(xreg[i][0][j]);
        v[4 + j] = (short)f2bf(xreg[i][1][j]);
      }
      *(short8*)&Xs[i * 32 + xm][xc * 8] = v;
    }
    *(short8*)&Ws[xm][xc * 8] = wreg[0];
    *(short8*)&Ws[32 + xm][xc * 8] = wreg[1];
    *(short8*)&Ws[64 + xm][xc * 8] = wreg[2];
    *(short8*)&Ws[96 + xm][xc * 8] = wreg[3];
    __syncthreads();

    // issue next tile's global loads; latency hides under MFMA phase below
    if (kt + 1 < C_ / GBK) {
      int koff = (kt + 1) * GBK + xc * 8;
      xreg[0][0] = *(const floatx4*)&xrow0[koff];
      xreg[0][1] = *(const floatx4*)&xrow0[koff + 4];
      xreg[1][0] = *(const floatx4*)&xrow1[koff];
      xreg[1][1] = *(const floatx4*)&xrow1[koff + 4];
      wreg[0] = *(const short8*)&wrow0[koff];
      wreg[1] = *(const short8*)&wrow1[koff];
      wreg[2] = *(const short8*)&wrow2[koff];
      wreg[3] = *(const short8*)&wrow3[koff];
    }

#pragma unroll
    for (int ks = 0; ks < 2; ++ks) {
      short8 af[2], bf[4];
#pragma unroll
      for (int mt = 0; mt < 2; ++mt)
        af[mt] = *(const short8*)&Xs[wm + mt * 16 + l15][ks * 32 + hi * 8];
#pragma unroll
      for (int nt = 0; nt < 4; ++nt)
        bf[nt] = *(const short8*)&Ws[wn + nt * 16 + l15][ks * 32 + hi * 8];
#pragma unroll
      for (int mt = 0; mt < 2; ++mt)
#pragma unroll
        for (int nt = 0; nt < 4; ++nt)
          acc[mt][nt] = __builtin_amdgcn_mfma_f32_16x16x32_bf16(
              af[mt], bf[nt], acc[mt][nt], 0, 0, 0);
    }
    __syncthreads();
  }

  if (z != 2) {
    u16* outp = qkv + (size_t)z * ((size_t)B_ * T_ * HS_);
#pragma unroll
    for (int mt = 0; mt < 2; ++mt)
#pragma unroll
      for (int nt = 0; nt < 4; ++nt)
#pragma unroll
        for (int r = 0; r < 4; ++r) {
          size_t row = mbase + wm + mt * 16 + hi * 4 + r;
          int col = wn + nt * 16 + l15;
          outp[row * HS_ + col] = f2bf(acc[mt][nt][r]);
        }
  } else {
    // V^T epilogue: transpose the 64x128 tile in LDS, write contiguous
    // 64-elem segments per vT row. Safe to overwrite smem (loop ended with
    // __syncthreads after the last MFMA reads).
    u16 (*Tb)[LPAD] = (u16(*)[LPAD])smem;  // [128][72] fits in the pool
#pragma unroll
    for (int mt = 0; mt < 2; ++mt)
#pragma unroll
      for (int nt = 0; nt < 4; ++nt)
#pragma unroll
        for (int r = 0; r < 4; ++r)
          Tb[wn + nt * 16 + l15][wm + mt * 16 + hi * 4 + r] = f2bf(acc[mt][nt][r]);
    __syncthreads();
    int b = (int)(mbase >> 12);            // T_ = 4096
    int trow0 = (int)(mbase & (T_ - 1));
    u16* vb = vT + (size_t)b * HS_ * T_;
#pragma unroll
    for (int i = 0; i < 4; ++i) {
      int id = i * 256 + t;
      int c = id >> 3, ch = id & 7;        // c: vT row (0..127), ch: 8-elem chunk
      short8 v = *(const short8*)&Tb[c][ch * 8];
      *(short8*)&vb[(size_t)c * T_ + trow0 + ch * 8] = v;
    }
  }
}

// ---------------------------------------------------------------- flash core
#define BQ 64
#define BKV 64
#define CHUNK 16  // KV tiles per split-KV block (1024 keys)

// Shared body: processes kv tiles [kb0, kb1] for (b, qb). If WRITE_PARTIAL,
// writes unnormalized O + (m,l); else normalizes and writes fp32 out.
template <bool WRITE_PARTIAL>
static __device__ __forceinline__ void flash_body(
    const u16* __restrict__ q, const u16* __restrict__ k,
    const u16* __restrict__ vT, float* __restrict__ outO,
    float* __restrict__ Mp, float* __restrict__ Lp,
    int b, int qb, int kb0, int kb1, int slot) {
  __shared__ u16 Ks[BKV][136];
  __shared__ u16 Vs[144][72];   // rows 0..127: V^T tile; rows 128..143: ones (l-column)
  __shared__ u16 Ps[BQ][72];
  int t = threadIdx.x;
  int wv = t >> 6, lane = t & 63, l15 = lane & 15, hi = lane >> 4;

  const float sc = 0.08838834764831845f * 1.4426950408889634f;

  short8 qf[4];
  {
    const u16* qrow = q + (size_t)(b * T_ + qb * BQ + wv * 16 + l15) * HS_;
#pragma unroll
    for (int ks = 0; ks < 4; ++ks)
      qf[ks] = *(const short8*)(qrow + ks * 32 + hi * 8);
  }

  // ones rows for MFMA l-accumulation: rows 128..143, cols 0..63 used by PV.
  {
    int r = 128 + (t >> 4), c0 = (t & 15) * 4;
    const u16 one = 0x3F80;  // bf16 1.0
    Vs[r][c0] = one; Vs[r][c0 + 1] = one;
    Vs[r][c0 + 2] = one; Vs[r][c0 + 3] = one;
  }

  floatx4 of[9];  // of[0..7] = O; of[8] = l (row-sum column)
#pragma unroll
  for (int dt = 0; dt < 9; ++dt) of[dt] = (floatx4){0.f, 0.f, 0.f, 0.f};
  float m_run[4];
#pragma unroll
  for (int r = 0; r < 4; ++r) m_run[r] = -__builtin_inff();

  const u16* kbase = k + (size_t)b * T_ * HS_;
  const u16* vbase = vT + (size_t)b * HS_ * T_;

  // ---- register prefetch of tile kb0
  short8 kreg[4], vreg[4];
#pragma unroll
  for (int i = 0; i < 4; ++i) {
    int id = i * 256 + t;
    int n = id >> 4, ck = id & 15;
    kreg[i] = *(const short8*)&kbase[(size_t)(kb0 * BKV + n) * HS_ + ck * 8];
    int d = id >> 3, cv = id & 7;
    vreg[i] = *(const short8*)&vbase[(size_t)d * T_ + kb0 * BKV + cv * 8];
  }

  for (int kb = kb0; kb <= kb1; ++kb) {
    // write staged registers -> LDS (vmcnt wait inserted by compiler)
#pragma unroll
    for (int i = 0; i < 4; ++i) {
      int id = i * 256 + t;
      int n = id >> 4, ck = id & 15;
      *(short8*)&Ks[n][ck * 8] = kreg[i];
      int d = id >> 3, cv = id & 7;
      *(short8*)&Vs[d][cv * 8] = vreg[i];
    }
    __syncthreads();

    // issue next tile's global loads early; results not needed until next
    // loop top, so their latency hides under QK/softmax/PV below.
    if (kb < kb1) {
#pragma unroll
      for (int i = 0; i < 4; ++i) {
        int id = i * 256 + t;
        int n = id >> 4, ck = id & 15;
        kreg[i] = *(const short8*)&kbase[(size_t)((kb + 1) * BKV + n) * HS_ + ck * 8];
        int d = id >> 3, cv = id & 7;
        vreg[i] = *(const short8*)&vbase[(size_t)d * T_ + (kb + 1) * BKV + cv * 8];
      }
    }

    floatx4 sf[4];
#pragma unroll
    for (int nt = 0; nt < 4; ++nt) {
      floatx4 s = (floatx4){0.f, 0.f, 0.f, 0.f};
#pragma unroll
      for (int ks = 0; ks < 4; ++ks) {
        short8 bfrag = *(const short8*)&Ks[nt * 16 + l15][ks * 32 + hi * 8];
        s = __builtin_amdgcn_mfma_f32_16x16x32_bf16(qf[ks], bfrag, s, 0, 0, 0);
      }
      sf[nt] = s;
    }

    float sv[4][4];
    if (kb == qb) {
#pragma unroll
      for (int nt = 0; nt < 4; ++nt) {
        int col = nt * 16 + l15;
#pragma unroll
        for (int r = 0; r < 4; ++r) {
          int row = wv * 16 + hi * 4 + r;
          sv[nt][r] = (col <= row) ? sf[nt][r] * sc : -__builtin_inff();
        }
      }
    } else {
#pragma unroll
      for (int nt = 0; nt < 4; ++nt)
#pragma unroll
        for (int r = 0; r < 4; ++r) sv[nt][r] = sf[nt][r] * sc;
    }

    // per-row max (4-step butterfly over the 16-lane group)
    float mt4[4];
#pragma unroll
    for (int r = 0; r < 4; ++r)
      mt4[r] = fmaxf(fmaxf(sv[0][r], sv[1][r]), fmaxf(sv[2][r], sv[3][r]));
#pragma unroll
    for (int off = 1; off < 16; off <<= 1)
#pragma unroll
      for (int r = 0; r < 4; ++r)
        mt4[r] = fmaxf(mt4[r], __shfl_xor(mt4[r], off));

    // defer-max: only rescale when a row max grew by > 8 (P bounded by 2^8)
    bool need = false;
#pragma unroll
    for (int r = 0; r < 4; ++r) need = need || (mt4[r] > m_run[r] + 8.f);
    if (__any(need)) {
      float alpha[4];
#pragma unroll
      for (int r = 0; r < 4; ++r) {
        float mn = fmaxf(m_run[r], mt4[r]);
        alpha[r] = exp2f(m_run[r] - mn);
        m_run[r] = mn;
      }
#pragma unroll
      for (int dt = 0; dt < 9; ++dt)
#pragma unroll
        for (int r = 0; r < 4; ++r) of[dt][r] *= alpha[r];
    }

    float pv[4][4];
#pragma unroll
    for (int nt = 0; nt < 4; ++nt)
#pragma unroll
      for (int r = 0; r < 4; ++r) pv[nt][r] = exp2f(sv[nt][r] - m_run[r]);

#pragma unroll
    for (int nt = 0; nt < 4; ++nt)
#pragma unroll
      for (int r = 0; r < 4; ++r)
        Ps[wv * 16 + hi * 4 + r][nt * 16 + l15] = f2bf(pv[nt][r]);
    __asm__ volatile("s_waitcnt lgkmcnt(0)" ::: "memory");

#pragma unroll
    for (int ks2 = 0; ks2 < 2; ++ks2) {
      short8 af = *(const short8*)&Ps[wv * 16 + l15][ks2 * 32 + hi * 8];
#pragma unroll
      for (int dt = 0; dt < 9; ++dt) {
        short8 bfrag = *(const short8*)&Vs[dt * 16 + l15][ks2 * 32 + hi * 8];
        of[dt] = __builtin_amdgcn_mfma_f32_16x16x32_bf16(af, bfrag, of[dt], 0, 0, 0);
      }
    }
    __syncthreads();
  }

  if (WRITE_PARTIAL) {
    float* Op = outO + (size_t)slot * (BQ * HS_);
#pragma unroll
    for (int dt = 0; dt < 8; ++dt)
#pragma unroll
      for (int r = 0; r < 4; ++r) {
        int row = wv * 16 + hi * 4 + r;
        Op[row * HS_ + dt * 16 + l15] = of[dt][r];
      }
    if (l15 == 0) {
#pragma unroll
      for (int r = 0; r < 4; ++r) {
        int row = wv * 16 + hi * 4 + r;
        Mp[slot * BQ + row] = m_run[r];
        Lp[slot * BQ + row] = of[8][r];  // l accumulated by MFMA ones-column
      }
    }
  } else {
    float rl[4];
#pragma unroll
    for (int r = 0; r < 4; ++r) rl[r] = 1.0f / of[8][r];
#pragma unroll
    for (int dt = 0; dt < 8; ++dt)
#pragma unroll
      for (int r = 0; r < 4; ++r) {
        size_t row = (size_t)(b * T_ + qb * BQ + wv * 16 + hi * 4 + r);
        outO[row * HS_ + dt * 16 + l15] = of[dt][r] * rl[r];
      }
  }
}

// split-KV partial: grid (64 qb, 4 chunk, 4 batch)
__global__ __launch_bounds__(256, 3) void flash_partial_kernel(
    const u16* __restrict__ q, const u16* __restrict__ k,
    const u16* __restrict__ vT, float* __restrict__ Opart,
    float* __restrict__ Mpart, float* __restrict__ Lpart) {
  int qb = blockIdx.x, c = blockIdx.y, b = blockIdx.z;
  int kb0 = c * CHUNK;
  if (kb0 > qb) return;  // empty chunk
  int kb1 = min(qb, kb0 + CHUNK - 1);
  int slot = (b * (T_ / BQ) + qb) * 4 + c;
  flash_body<true>(q, k, vT, Opart, Mpart, Lpart, b, qb, kb0, kb1, slot);
}

// monolithic fallback: grid (64 qb, 4 batch)
__global__ __launch_bounds__(256, 3) void flash_attn_kernel(
    const u16* __restrict__ q, const u16* __restrict__ k,
    const u16* __restrict__ vT, float* __restrict__ out) {
  int qb = blockIdx.x, b = blockIdx.y;
  flash_body<false>(q, k, vT, out, nullptr, nullptr, b, qb, 0, qb, 0);
}

// merge: grid (64 qb, 4 batch), 256 threads
__global__ __launch_bounds__(256) void flash_merge_kernel(
    const float* __restrict__ Opart, const float* __restrict__ Mpart,
    const float* __restrict__ Lpart, float* __restrict__ out) {
  __shared__ float w[4][BQ];
  __shared__ float invL[BQ];
  int qb = blockIdx.x, b = blockIdx.y;
  int t = threadIdx.x;
  int nch = qb / CHUNK + 1;  // 1..4
  int slot0 = (b * (T_ / BQ) + qb) * 4;

  if (t < BQ) {
    float mv[4], mmax = -__builtin_inff();
    for (int c = 0; c < nch; ++c) {
      mv[c] = Mpart[(slot0 + c) * BQ + t];
      mmax = fmaxf(mmax, mv[c]);
    }
    float L = 0.f;
    for (int c = 0; c < nch; ++c) {
      float wc = exp2f(mv[c] - mmax);
      w[c][t] = wc;
      L += wc * Lpart[(slot0 + c) * BQ + t];
    }
    invL[t] = 1.0f / L;
  }
  __syncthreads();

  size_t obase = ((size_t)(b * T_) + (size_t)qb * BQ) * HS_;
#pragma unroll
  for (int j = 0; j < 32; ++j) {
    int e = j * 256 + t;           // 0..8191
    int row = e >> 7;
    float acc = 0.f;
    for (int c = 0; c < nch; ++c)
      acc += w[c][row] * Opart[(size_t)(slot0 + c) * (BQ * HS_) + e];
    out[obase + e] = acc * invL[row];
  }
}

// ---------------------------------------------------------------- launch
extern "C" void kernel_launch(void* const* d_in, const int* in_sizes, int n_in,
                              void* d_out, int out_size, void* d_ws, size_t ws_size,
                              hipStream_t stream) {
  const float* x  = (const float*)d_in[0];
  const float* Wq = (const float*)d_in[1];
  const float* Wk = (const float*)d_in[2];
  const float* Wv = (const float*)d_in[3];
  float* out = (float*)d_out;

  u16* ws = (u16*)d_ws;
  const size_t wtsz  = (size_t)HS_ * C_;
  const size_t qkvsz = (size_t)B_ * T_ * HS_;
  u16* WT = ws;
  u16* qv = WT + 3 * wtsz;
  u16* kv = qv + qkvsz;
  u16* vT = kv + qkvsz;
  const size_t base_bytes = (3 * wtsz + 3 * qkvsz) * sizeof(u16);  // 14,155,776

  const int NSLOT = B_ * (T_ / BQ) * 4;  // 1024
  float* Opart = (float*)((char*)d_ws + base_bytes);
  float* Mpart = Opart + (size_t)NSLOT * BQ * HS_;
  float* Lpart = Mpart + (size_t)NSLOT * BQ;
  const size_t split_bytes =
      base_bytes + ((size_t)NSLOT * BQ * HS_ + 2 * (size_t)NSLOT * BQ) * sizeof(float);

  dim3 tb(32, 8);
  wtrans3_kernel<<<dim3(HS_ / 32, C_ / 32, 3), tb, 0, stream>>>(Wq, Wk, Wv, WT);

  qkv_gemm_kernel<<<dim3((B_ * T_) / GBM, 3), 256, 0, stream>>>(x, WT, qv, vT);

  if (ws_size >= split_bytes) {
    flash_partial_kernel<<<dim3(T_ / BQ, 4, B_), 256, 0, stream>>>(
        qv, kv, vT, Opart, Mpart, Lpart);
    flash_merge_kernel<<<dim3(T_ / BQ, B_), 256, 0, stream>>>(
        Opart, Mpart, Lpart, out);
  } else {
    flash_attn_kernel<<<dim3(T_ / BQ, B_), 256, 0, stream>>>(qv, kv, vT, out);
  }
}